// Round 16
// baseline (6570.762 us; speedup 1.0000x reference)
//
#include <hip/hip_runtime.h>
#include <hip/hip_bf16.h>

#define T_STEPS 128
#define DH      512
#define NPATCH  196
#define BATCH   16
#define VOCAB   10000
#define NB5     64

typedef __attribute__((ext_vector_type(8))) short bf16x8;
typedef __attribute__((ext_vector_type(4))) float f32x4;

__device__ __forceinline__ float sigm(float x) { return 1.0f / (1.0f + __expf(-x)); }
__device__ __forceinline__ float ftanh(float x) {
    float e = __expf(2.0f * x);
    return 1.0f - 2.0f / (e + 1.0f);
}
__device__ __forceinline__ unsigned short f2b(float x) {
    union { float f; unsigned u; } v; v.f = x;
    unsigned r = (v.u + 0x7FFFu + ((v.u >> 16) & 1u)) >> 16;
    return (unsigned short)r;
}
__device__ __forceinline__ float b2f(unsigned short h) {
    union { unsigned u; float f; } v; v.u = ((unsigned)h) << 16;
    return v.f;
}
// L2-bypassing coherent access (r10/r13/r15-proven): relaxed agent atomics -> sc0 sc1.
__device__ __forceinline__ float cload(const float* p) {
    return __hip_atomic_load(p, __ATOMIC_RELAXED, __HIP_MEMORY_SCOPE_AGENT);
}
__device__ __forceinline__ void cstore(float* p, float v) {
    __hip_atomic_store(p, v, __ATOMIC_RELAXED, __HIP_MEMORY_SCOPE_AGENT);
}
// Vector (16B) cache-bypass ops via ext_vector operands (r15-proven).
__device__ __forceinline__ f32x4 cload4(const float* p) {
    f32x4 v;
    asm volatile("global_load_dwordx4 %0, %1, off sc0 sc1\n\ts_waitcnt vmcnt(0)"
                 : "=&v"(v) : "v"(p) : "memory");
    return v;
}
__device__ __forceinline__ void cload4x2(const float* p0, const float* p1, f32x4& a, f32x4& b) {
    asm volatile("global_load_dwordx4 %0, %2, off sc0 sc1\n\t"
                 "global_load_dwordx4 %1, %3, off sc0 sc1\n\t"
                 "s_waitcnt vmcnt(0)"
                 : "=&v"(a), "=&v"(b) : "v"(p0), "v"(p1) : "memory");
}
__device__ __forceinline__ void cstore4(float* p, f32x4 v) {
    asm volatile("global_store_dwordx4 %0, %1, off sc0 sc1" :: "v"(p), "v"(v) : "memory");
}

// ---------------- conversion kernels ----------------
__global__ __launch_bounds__(256)
void cvt_kernel(const float* __restrict__ src, unsigned short* __restrict__ dst, int n)
{
    int i = (blockIdx.x * 256 + threadIdx.x) * 8;
    if (i >= n) return;
    float4 v0 = *(const float4*)(src + i);
    float4 v1 = *(const float4*)(src + i + 4);
    float xs[8] = {v0.x, v0.y, v0.z, v0.w, v1.x, v1.y, v1.z, v1.w};
    bf16x8 o;
#pragma unroll
    for (int j = 0; j < 8; ++j) o[j] = (short)f2b(xs[j]);
    *(bf16x8*)(dst + i) = o;
}

__global__ __launch_bounds__(256)
void cvt_split_kernel(const float* __restrict__ src, unsigned short* __restrict__ hi,
                      unsigned short* __restrict__ lo, int n)
{
    int i = (blockIdx.x * 256 + threadIdx.x) * 8;
    if (i >= n) return;
    float4 v0 = *(const float4*)(src + i);
    float4 v1 = *(const float4*)(src + i + 4);
    float xs[8] = {v0.x, v0.y, v0.z, v0.w, v1.x, v1.y, v1.z, v1.w};
    bf16x8 h_, l_;
#pragma unroll
    for (int j = 0; j < 8; ++j) {
        unsigned short hb = f2b(xs[j]);
        float r = xs[j] - b2f(hb);
        h_[j] = (short)hb;
        l_[j] = (short)f2b(r);
    }
    *(bf16x8*)(hi + i) = h_;
    *(bf16x8*)(lo + i) = l_;
}

// Wx[j][k] = Wih[j][k], k<512 (x-columns), split
__global__ __launch_bounds__(256)
void cvt_wx_kernel(const float* __restrict__ Wih, unsigned short* __restrict__ WxH,
                   unsigned short* __restrict__ WxL)
{
    int i = (blockIdx.x * 256 + threadIdx.x) * 8;
    if (i >= 2048 * 512) return;
    int j = i >> 9, k = i & 511;
    const float* s = Wih + (size_t)j * 1024 + k;
    float4 v0 = *(const float4*)s, v1 = *(const float4*)(s + 4);
    float xs[8] = {v0.x, v0.y, v0.z, v0.w, v1.x, v1.y, v1.z, v1.w};
    bf16x8 h_, l_;
#pragma unroll
    for (int q = 0; q < 8; ++q) {
        unsigned short hb = f2b(xs[q]);
        h_[q] = (short)hb;
        l_[q] = (short)f2b(xs[q] - b2f(hb));
    }
    *(bf16x8*)(WxH + i) = h_;
    *(bf16x8*)(WxL + i) = l_;
}

// ---------------- MFMA GEMM (3-term split; verified round 4) ----------------
__global__ __launch_bounds__(256)
void gemm_mfma(const unsigned short* __restrict__ AH, const unsigned short* __restrict__ AL,
               const unsigned short* __restrict__ WH, const unsigned short* __restrict__ WL,
               const float* __restrict__ bias, float* __restrict__ C,
               unsigned short* __restrict__ CbH, unsigned short* __restrict__ CbL,
               int M, int N, int K)
{
    const int tid = threadIdx.x, wid = tid >> 6, l = tid & 63;
    const int m0 = blockIdx.x * 128 + (wid >> 1) * 64;
    const int n0 = blockIdx.y * 128 + (wid & 1) * 64;
    const int lm = l & 15, lk = (l >> 4) * 8;
    f32x4 acc[4][4];
#pragma unroll
    for (int i = 0; i < 4; ++i)
#pragma unroll
        for (int j = 0; j < 4; ++j) acc[i][j] = (f32x4){0.f, 0.f, 0.f, 0.f};
    const bf16x8 az = {0,0,0,0,0,0,0,0};

    for (int k0 = 0; k0 < K; k0 += 32) {
        bf16x8 aH[4], aL[4];
#pragma unroll
        for (int mi = 0; mi < 4; ++mi) {
            int m = m0 + mi * 16 + lm;
            aH[mi] = (m < M) ? *(const bf16x8*)(AH + (size_t)m * K + k0 + lk) : az;
            aL[mi] = (AL && m < M) ? *(const bf16x8*)(AL + (size_t)m * K + k0 + lk) : az;
        }
#pragma unroll
        for (int ni = 0; ni < 4; ++ni) {
            int n = n0 + ni * 16 + lm;
            bf16x8 bH = az, bL = az;
            if (n < N) {
                bH = *(const bf16x8*)(WH + (size_t)n * K + k0 + lk);
                if (WL) bL = *(const bf16x8*)(WL + (size_t)n * K + k0 + lk);
            }
#pragma unroll
            for (int mi = 0; mi < 4; ++mi) {
                acc[mi][ni] = __builtin_amdgcn_mfma_f32_16x16x32_bf16(aH[mi], bH, acc[mi][ni], 0, 0, 0);
                if (WL) acc[mi][ni] = __builtin_amdgcn_mfma_f32_16x16x32_bf16(aH[mi], bL, acc[mi][ni], 0, 0, 0);
                if (AL) acc[mi][ni] = __builtin_amdgcn_mfma_f32_16x16x32_bf16(aL[mi], bH, acc[mi][ni], 0, 0, 0);
            }
        }
    }
    const int rr = (l >> 4) * 4;
#pragma unroll
    for (int mi = 0; mi < 4; ++mi) {
        int mb = m0 + mi * 16 + rr;
#pragma unroll
        for (int ni = 0; ni < 4; ++ni) {
            int n = n0 + ni * 16 + lm;
            if (n < N) {
                float bs = bias ? bias[n] : 0.f;
#pragma unroll
                for (int r = 0; r < 4; ++r) {
                    int mm = mb + r;
                    if (mm < M) {
                        float v = acc[mi][ni][r] + bs;
                        if (C)   C[(size_t)mm * N + n] = v;
                        if (CbH) {
                            unsigned short hb = f2b(v);
                            CbH[(size_t)mm * N + n] = hb;
                            if (CbL) CbL[(size_t)mm * N + n] = f2b(v - b2f(hb));
                        }
                    }
                }
            }
        }
    }
}

// ---------------- h0 / c0 (fp32) ----------------
__global__ __launch_bounds__(256)
void h0c0_kernel(const float* __restrict__ cls,
                 const float* __restrict__ ihw, const float* __restrict__ ihb,
                 const float* __restrict__ icw, const float* __restrict__ icb,
                 float* __restrict__ c_g, float* __restrict__ h_raw0)
{
    int id = blockIdx.x * 256 + threadIdx.x;
    int which = id >> 13;
    int b = (id >> 9) & 15;
    int d = id & 511;
    const float* w = (which ? icw : ihw) + d * 768;
    const float* x = cls + b * 768;
    float acc = which ? icb[d] : ihb[d];
    const float4* x4 = (const float4*)x;
    const float4* w4 = (const float4*)w;
#pragma unroll 4
    for (int k = 0; k < 192; ++k) {
        float4 a = x4[k], ww = w4[k];
        acc += a.x * ww.x + a.y * ww.y + a.z * ww.z + a.w * ww.w;
    }
    if (which) c_g[b * 512 + d] = acc;
    else h_raw0[b * 512 + d] = acc;
}

// x split gather (feeds XG GEMM)
__global__ __launch_bounds__(256)
void gather_kernel(const int* __restrict__ ids, const float* __restrict__ emb,
                   unsigned short* __restrict__ xH, unsigned short* __restrict__ xL)
{
    int q = blockIdx.x * 256 + threadIdx.x;
    if (q >= 2048 * 64) return;
    int r = q >> 6, c = (q & 63) * 8;
    int tgt = ids[r];
    const float4* s = (const float4*)(emb + (size_t)tgt * 512 + c);
    float4 v0 = s[0], v1 = s[1];
    float xs[8] = {v0.x, v0.y, v0.z, v0.w, v1.x, v1.y, v1.z, v1.w};
    bf16x8 oh, ol;
#pragma unroll
    for (int j = 0; j < 8; ++j) {
        unsigned short hb = f2b(xs[j]);
        oh[j] = (short)hb;
        ol[j] = (short)f2b(xs[j] - b2f(hb));
    }
    *(bf16x8*)(xH + (size_t)r * 512 + c) = oh;
    *(bf16x8*)(xL + (size_t)r * 512 + c) = ol;
}

// ---------------- grid store/poll barrier (r15-proven) ----------------
__device__ __forceinline__ void grid_bar(int* slots, int gen)
{
    __syncthreads();
    if (threadIdx.x < 64) {
        if (threadIdx.x == 0)
            __hip_atomic_store(&slots[blockIdx.x], gen, __ATOMIC_RELAXED, __HIP_MEMORY_SCOPE_AGENT);
        while (__hip_atomic_load(&slots[threadIdx.x], __ATOMIC_RELAXED, __HIP_MEMORY_SCOPE_AGENT) < gen)
            __builtin_amdgcn_s_sleep(1);
    }
    __syncthreads();
}

// ---------------- persistent recurrence v7: 2 phases, 2 grid barriers/step ----------
// 64 blocks x 1024 thr. Block k: batch b_own=k&15 (4 same-batch blocks share an XCD
// under round-robin: k≡b mod 8), ctx quarter q=k>>4, d-octet [8k,8k+8) for gates.
// P123: LN + FULL ew + FULL scores + softmax (redundant per block, all in LDS;
//       ~1us extra compute <<< 2 barrier round-trips saved) + ctx quarter publish.
// P4:   stage all 16 batches' z at once (bypass dwordx4), gates from registers, cell.
__global__ __launch_bounds__(1024, 1)
void recur7_kernel(float* __restrict__ ctx, float* __restrict__ hln_g,
                   float* __restrict__ h_raw2, float* __restrict__ c_g,
                   float* __restrict__ partials2,
                   const float* __restrict__ keys, const float* __restrict__ keysWk,
                   const float* __restrict__ XG,
                   const float* __restrict__ Wih, const float* __restrict__ Whh,
                   const float* __restrict__ bih, const float* __restrict__ bhh,
                   const float* __restrict__ Wh, const float* __restrict__ lng,
                   const float* __restrict__ lnb, const float* __restrict__ vvec,
                   unsigned short* __restrict__ h_all_b, int* __restrict__ bar)
{
    __shared__ float zs[16][1024];         // 64KB: z=[ctx|hln] all 16 batches
    __shared__ float hv[512], ewS[512], vvS[512];
    __shared__ float scS[200], alS[200];
    __shared__ float pb[8][128];
    __shared__ float gbuf[16][32];
    __shared__ float bias_l[32], red[32];

    const int k = blockIdx.x, tid = threadIdx.x;
    const int b_own = k & 15, q = k >> 4;
    const int rrow = tid >> 5, ks = tid & 31;

    // one-time: gate weights K=1024 ([Wih ctx-cols | Whh]) into registers
    float wreg[32];
    {
        int g = rrow >> 3, dd = rrow & 7;
        int j = g * 512 + 8 * k + dd;
        const float* wc = Wih + (size_t)j * 1024 + 512;
        const float* wh2 = Whh + (size_t)j * 512;
#pragma unroll
        for (int i = 0; i < 32; ++i) {
            int kk = ks + 32 * i;
            wreg[i] = (kk < 512) ? wc[kk] : wh2[kk - 512];
        }
        if (tid < 32) {
            int g2 = tid >> 3, dd2 = tid & 7, j2 = g2 * 512 + 8 * k + dd2;
            bias_l[tid] = bih[j2] + bhh[j2];
        }
        if (tid < 512) vvS[tid] = vvec[tid];
    }
    __syncthreads();

    int gen = 0;
    for (int t = 0; t < T_STEPS; ++t) {
        const float* hcur = h_raw2 + (t & 1) * (BATCH * 512);
        float* hnxt = h_raw2 + ((t + 1) & 1) * (BATCH * 512);
        const float* pcur = partials2 + (t & 1) * (BATCH * 64 * 2);
        float* pnxt = partials2 + ((t + 1) & 1) * (BATCH * 64 * 2);

        // ===== P123: LN + full ew + full scores + softmax + ctx quarter =====
        if (t > 0) {
            if (tid < 64) {
                const float* pp = pcur + ((size_t)b_own * 64 + tid) * 2;
                float s1 = cload(pp), s2 = cload(pp + 1);
#pragma unroll
                for (int m = 1; m < 64; m <<= 1) { s1 += __shfl_xor(s1, m); s2 += __shfl_xor(s2, m); }
                if (tid == 0) {
                    float mu = s1 * (1.f / 512.f);
                    float var = s2 * (1.f / 512.f) - mu * mu;
                    red[0] = mu; red[1] = rsqrtf(var + 1e-5f);
                }
            }
        } else if (tid == 0) { red[0] = 0.f; red[1] = 1.f; }
        __syncthreads();
        if (tid < 128) {
            f32x4 h4 = cload4(hcur + b_own * 512 + tid * 4);
            f32x4 o = h4;
            if (t > 0) {
                float mu = red[0], rv = red[1];
                f32x4 g4 = ((const f32x4*)lng)[tid];
                f32x4 bl4 = ((const f32x4*)lnb)[tid];
#pragma unroll
                for (int u = 0; u < 4; ++u) o[u] = (h4[u] - mu) * rv * g4[u] + bl4[u];
            }
            ((f32x4*)hv)[tid] = o;
            if (q == 0) {
                cstore4(&hln_g[b_own * 512 + tid * 4], o);
                if (t > 0) {
                    short4 hb = { (short)f2b(o[0]), (short)f2b(o[1]), (short)f2b(o[2]), (short)f2b(o[3]) };
                    *(short4*)(h_all_b + ((size_t)b_own * T_STEPS + (t - 1)) * 512 + tid * 4) = hb;
                }
            }
        }
        __syncthreads();
        {   // FULL ew: 4 passes x 128 e, 8 thr/e, coalesced; Wh (1MB) L2-shared per XCD
            int g8 = tid & 7;
#pragma unroll
            for (int pass = 0; pass < 4; ++pass) {
                int e = pass * 128 + (tid >> 3);
                const float4* wr4 = (const float4*)(Wh + (size_t)e * 512);
                float s = 0.f;
#pragma unroll
                for (int i = 0; i < 16; ++i) {
                    int k4 = g8 + 8 * i;
                    float4 w4 = wr4[k4];
                    float4 h4 = ((const float4*)hv)[k4];
                    s += w4.x * h4.x + w4.y * h4.y + w4.z * h4.z + w4.w * h4.w;
                }
                s += __shfl_xor(s, 1); s += __shfl_xor(s, 2); s += __shfl_xor(s, 4);
                if (g8 == 0) ewS[e] = s;
            }
        }
        __syncthreads();
        {   // FULL scores: 2 passes x 128 n (n<196), 8 thr/n
            int g8 = tid & 7;
#pragma unroll
            for (int pass = 0; pass < 2; ++pass) {
                int n = pass * 128 + (tid >> 3);
                if (n < NPATCH) {
                    const float4* kw4 = (const float4*)(keysWk + ((size_t)(b_own * NPATCH + n)) * 512);
                    float s = 0.f;
#pragma unroll
                    for (int i = 0; i < 16; ++i) {
                        int k4 = g8 + 8 * i;
                        float4 kk = kw4[k4];
                        int d0 = k4 * 4;
                        s += ftanh(ewS[d0 + 0] + kk.x) * vvS[d0 + 0]
                           + ftanh(ewS[d0 + 1] + kk.y) * vvS[d0 + 1]
                           + ftanh(ewS[d0 + 2] + kk.z) * vvS[d0 + 2]
                           + ftanh(ewS[d0 + 3] + kk.w) * vvS[d0 + 3];
                    }
                    s += __shfl_xor(s, 1); s += __shfl_xor(s, 2); s += __shfl_xor(s, 4);
                    if (g8 == 0) scS[n] = s;
                }
            }
        }
        __syncthreads();
        {   // softmax + ctx quarter
            float sv = (tid < NPATCH) ? scS[tid] : -1e30f;
            float m1 = sv;
#pragma unroll
            for (int m = 1; m < 64; m <<= 1) m1 = fmaxf(m1, __shfl_xor(m1, m));
            if ((tid & 63) == 0 && tid < 256) red[8 + (tid >> 6)] = m1;
            __syncthreads();
            float mx = fmaxf(fmaxf(red[8], red[9]), fmaxf(red[10], red[11]));
            float ev = (tid < NPATCH) ? __expf(sv - mx) : 0.f;
            if (tid < NPATCH) alS[tid] = ev;
            float s2 = ev;
#pragma unroll
            for (int m = 1; m < 64; m <<= 1) s2 += __shfl_xor(s2, m);
            if ((tid & 63) == 0 && tid < 256) red[12 + (tid >> 6)] = s2;
            __syncthreads();
            float inv = 1.f / (red[12] + red[13] + red[14] + red[15]);
            int d_loc = tid & 127, g8 = tid >> 7;
            const float* kb = keys + (size_t)(b_own * NPATCH) * 512 + q * 128 + d_loc;
            float acc = 0.f;
            for (int n = g8; n < NPATCH; n += 8) acc += alS[n] * kb[(size_t)n * 512];
            pb[g8][d_loc] = acc;
            __syncthreads();
            if (tid < 128) {
                float s = 0.f;
#pragma unroll
                for (int g = 0; g < 8; ++g) s += pb[g][tid];
                cstore(&ctx[b_own * 512 + q * 128 + tid], s * inv);
            }
        }
        grid_bar(bar, ++gen);

        // ===== P4: stage all z at once + gates (reg weights) + cell =====
        {   // 16 batches x 1024 floats; thread: batch bb=tid>>6, 16 floats at off
            int bb = tid >> 6, off = (tid & 63) * 16;
            const float* src = (off < 512) ? &ctx[bb * 512 + off] : &hln_g[bb * 512 + (off - 512)];
            f32x4 a0, a1, a2, a3;
            cload4x2(src, src + 4, a0, a1);
            cload4x2(src + 8, src + 12, a2, a3);
            f32x4* dst = (f32x4*)&zs[bb][off];
            dst[0] = a0; dst[1] = a1; dst[2] = a2; dst[3] = a3;
        }
        __syncthreads();
#pragma unroll
        for (int bl = 0; bl < 16; ++bl) {
            float acc = 0.f;
#pragma unroll
            for (int i = 0; i < 32; ++i) acc += wreg[i] * zs[bl][ks + 32 * i];
#pragma unroll
            for (int m = 1; m < 32; m <<= 1) acc += __shfl_xor(acc, m);
            if (ks == 0) gbuf[bl][rrow] = acc;
        }
        __syncthreads();
        if (tid < 128) {
            int bp = tid >> 3, dd = tid & 7, d = 8 * k + dd;
            const float* xg = XG + ((size_t)bp * T_STEPS + t) * 2048;
            float gi = gbuf[bp][dd]      + bias_l[dd]      + xg[d];
            float gf = gbuf[bp][8 + dd]  + bias_l[8 + dd]  + xg[512 + d];
            float gg = gbuf[bp][16 + dd] + bias_l[16 + dd] + xg[1024 + d];
            float go = gbuf[bp][24 + dd] + bias_l[24 + dd] + xg[1536 + d];
            float cn = sigm(gf) * c_g[bp * 512 + d] + sigm(gi) * ftanh(gg);
            c_g[bp * 512 + d] = cn;              // block-private: cached
            float hr = sigm(go) * ftanh(cn);
            cstore(&hnxt[bp * 512 + d], hr);
            float s1 = hr, s2 = hr * hr;
#pragma unroll
            for (int m = 1; m < 8; m <<= 1) { s1 += __shfl_xor(s1, m); s2 += __shfl_xor(s2, m); }
            if (dd == 0) {
                cstore(&pnxt[((size_t)bp * 64 + k) * 2 + 0], s1);
                cstore(&pnxt[((size_t)bp * 64 + k) * 2 + 1], s2);
            }
        }
        grid_bar(bar, ++gen);
    }

    // tail: final LN -> h_all row 127 (q==0 blocks, b = b_own)
    if (q == 0) {
        const float* hcur = h_raw2 + (T_STEPS & 1) * (BATCH * 512);
        const float* pcur = partials2 + (T_STEPS & 1) * (BATCH * 64 * 2);
        int b = b_own;
        if (tid < 64) {
            const float* pp = pcur + ((size_t)b * 64 + tid) * 2;
            float s1 = cload(pp), s2 = cload(pp + 1);
#pragma unroll
            for (int m = 1; m < 64; m <<= 1) { s1 += __shfl_xor(s1, m); s2 += __shfl_xor(s2, m); }
            if (tid == 0) {
                float mu = s1 * (1.f / 512.f);
                float var = s2 * (1.f / 512.f) - mu * mu;
                red[0] = mu; red[1] = rsqrtf(var + 1e-5f);
            }
        }
        __syncthreads();
        if (tid < 128) {
            f32x4 h4 = cload4(hcur + b * 512 + tid * 4);
            float mu = red[0], rv = red[1];
            f32x4 g4 = ((const f32x4*)lng)[tid];
            f32x4 bl4 = ((const f32x4*)lnb)[tid];
            f32x4 o;
#pragma unroll
            for (int u = 0; u < 4; ++u) o[u] = (h4[u] - mu) * rv * g4[u] + bl4[u];
            short4 hb = { (short)f2b(o[0]), (short)f2b(o[1]), (short)f2b(o[2]), (short)f2b(o[3]) };
            *(short4*)(h_all_b + ((size_t)b * T_STEPS + (T_STEPS - 1)) * 512 + tid * 4) = hb;
        }
    }
}

extern "C" void kernel_launch(void* const* d_in, const int* in_sizes, int n_in,
                              void* d_out, int out_size, void* d_ws, size_t ws_size,
                              hipStream_t stream)
{
    const float* patches = (const float*)d_in[0];
    const float* cls     = (const float*)d_in[1];
    const int*   tgt     = (const int*)d_in[2];
    const float* kv_w    = (const float*)d_in[3];
    const float* kv_b    = (const float*)d_in[4];
    const float* ih_w    = (const float*)d_in[5];
    const float* ih_b    = (const float*)d_in[6];
    const float* ic_w    = (const float*)d_in[7];
    const float* ic_b    = (const float*)d_in[8];
    const float* emb     = (const float*)d_in[9];
    const float* Wh      = (const float*)d_in[10];
    const float* Wk      = (const float*)d_in[11];
    const float* av      = (const float*)d_in[12];
    const float* Wih     = (const float*)d_in[13];
    const float* Whh     = (const float*)d_in[14];
    const float* bih     = (const float*)d_in[15];
    const float* bhh     = (const float*)d_in[16];
    const float* lng     = (const float*)d_in[17];
    const float* lnb     = (const float*)d_in[18];
    const float* outw    = (const float*)d_in[19];
    const float* outb    = (const float*)d_in[20];
    float* out = (float*)d_out;

    char* wsp = (char*)d_ws;
    auto carve = [&](size_t bytes) -> char* {
        char* p = wsp; wsp += (bytes + 255) & ~(size_t)255; return p;
    };
    float*          keys_f   = (float*)carve((size_t)3136 * 512 * 4);
    float*          keysWk_f = (float*)carve((size_t)3136 * 512 * 4);
    unsigned short* keysH    = (unsigned short*)carve((size_t)3136 * 512 * 2);
    unsigned short* keysL    = (unsigned short*)carve((size_t)3136 * 512 * 2);
    unsigned short* xH       = (unsigned short*)carve((size_t)2048 * 512 * 2);
    unsigned short* xL       = (unsigned short*)carve((size_t)2048 * 512 * 2);
    unsigned short* h_all_b  = (unsigned short*)carve((size_t)2048 * 512 * 2);
    unsigned short* wxH      = (unsigned short*)carve((size_t)2048 * 512 * 2);
    unsigned short* wxL      = (unsigned short*)carve((size_t)2048 * 512 * 2);
    unsigned short* kvwH     = (unsigned short*)carve((size_t)512 * 768 * 2);
    unsigned short* kvwL     = (unsigned short*)carve((size_t)512 * 768 * 2);
    unsigned short* wkH      = (unsigned short*)carve((size_t)512 * 512 * 2);
    unsigned short* wkL      = (unsigned short*)carve((size_t)512 * 512 * 2);
    char*           R1       = carve((size_t)2048 * 2048 * 4);
    float* ctx      = (float*)carve((size_t)16 * 512 * 4);
    float* hln_g    = (float*)carve((size_t)16 * 512 * 4);
    float* h_raw2   = (float*)carve((size_t)2 * 16 * 512 * 4);
    float* c_g      = (float*)carve((size_t)16 * 512 * 4);
    float* partials2= (float*)carve((size_t)2 * 16 * 64 * 2 * 4);
    int*   bar      = (int*)carve(8192);
    unsigned short* patH   = (unsigned short*)R1;
    unsigned short* patL   = (unsigned short*)R1 + (size_t)3136 * 768;
    float*          XG     = (float*)R1;
    unsigned short* outw_b = (unsigned short*)R1;

    (void)hipMemsetAsync(bar, 0, 8192, stream);

    auto cvt = [&](const float* s, unsigned short* d, int n) {
        cvt_kernel<<<(n / 8 + 255) / 256, 256, 0, stream>>>(s, d, n);
    };
    auto cvts = [&](const float* s, unsigned short* dh, unsigned short* dl, int n) {
        cvt_split_kernel<<<(n / 8 + 255) / 256, 256, 0, stream>>>(s, dh, dl, n);
    };
    cvts(patches, patH, patL, 3136 * 768);
    cvts(kv_w, kvwH, kvwL, 512 * 768);
    cvts(Wk, wkH, wkL, 512 * 512);
    cvt_wx_kernel<<<512, 256, 0, stream>>>(Wih, wxH, wxL);
    gather_kernel<<<512, 256, 0, stream>>>(tgt, emb, xH, xL);

    // keys = patches @ kv_w^T + kv_b : fp32 + split-bf16 outputs (reads R1=patches)
    gemm_mfma<<<dim3(25, 4), 256, 0, stream>>>(patH, patL, kvwH, kvwL, kv_b,
                                               keys_f, keysH, keysL, 3136, 512, 768);
    // keysWk = keys @ Wk^T : fp32 out
    gemm_mfma<<<dim3(25, 4), 256, 0, stream>>>(keysH, keysL, wkH, wkL, nullptr,
                                               keysWk_f, nullptr, nullptr, 3136, 512, 512);
    // XG = x @ Wx^T (2048 x 2048, K=512) -> writes R1 (patches dead)
    gemm_mfma<<<dim3(16, 16), 256, 0, stream>>>(xH, xL, wxH, wxL, nullptr,
                                                XG, nullptr, nullptr, 2048, 2048, 512);

    h0c0_kernel<<<64, 256, 0, stream>>>(cls, ih_w, ih_b, ic_w, ic_b, c_g, h_raw2);

    // persistent recurrence: 64 blocks, 2 grid store/poll barriers per step
    recur7_kernel<<<NB5, 1024, 0, stream>>>(ctx, hln_g, h_raw2, c_g, partials2,
                                            keys_f, keysWk_f, XG, Wih, Whh, bih, bhh, Wh,
                                            lng, lnb, av, h_all_b, bar);

    // R1 free (XG dead): outw -> bf16, then logits GEMM
    cvt(outw, outw_b, VOCAB * 512);
    gemm_mfma<<<dim3(16, 79), 256, 0, stream>>>(h_all_b, nullptr, outw_b, nullptr, outb,
                                                out, nullptr, nullptr, 2048, VOCAB, 512);
}